// Round 8
// baseline (49.548 us; speedup 1.0000x reference)
//
#include <hip/hip_runtime.h>
#include <math.h>

#define N 2048
#define NN (N * N)
#define TAPS 49
#define ORANGE 17                       // tmax candidates: other-offset in [-8,8]
#define CB 137                          // producer blocks: CB*256 = 35072 >= (N+7)*17
#define MAGIC 0x5AFE600D
#define GRID (NN / 4 / 256)             // 4096 blocks, 1 quad/thread

typedef float f4 __attribute__((ext_vector_type(4)));

// ws layout (int words): [0..CB)   per-block band-max float bits (atomicExch)
//                        [256..256+CB) publish flags (MAGIC when value valid)
// Replay-safe: values are deterministic, so stale entries from a previous call
// are bitwise-identical; poison 0xAAAAAAAA != MAGIC gates the first call.

struct LineP {
    int steep, X0, Y0, SX, SY, DX, DY, cnt, ex, ey;
    float X0f, Y0f, SYf, SXf, slope;
};

__device__ inline LineP load_params(const float* x0p, const float* y0p,
                                    const float* x1p, const float* y1p) {
    float x0s = x0p[0], y0s = y0p[0], x1s = x1p[0], y1s = y1p[0];
    float dxf = fabsf(x1s - x0s), dyf = fabsf(y1s - y0s);
    bool steep = dyf > dxf;
    float sx = (x1s > x0s) ? 1.f : -1.f;
    float sy = (y1s > y0s) ? 1.f : -1.f;
    LineP p;
    p.steep = steep;
    p.X0 = (int)(steep ? y0s : x0s);
    p.Y0 = (int)(steep ? x0s : y0s);
    p.DX = (int)(steep ? dyf : dxf);
    p.DY = (int)(steep ? dxf : dyf);
    p.SX = (int)(steep ? sy : sx);
    p.SY = (int)(steep ? sx : sy);
    p.cnt = p.DX < N ? p.DX : N;           // line pixels are i in [0, cnt)
    int e = (int)((float)N * y1s + x1s);   // exact in f32 (< 2^23)
    e = e < 0 ? 0 : (e > NN - 1 ? NN - 1 : e);
    p.ey = e >> 11;
    p.ex = e & (N - 1);
    p.X0f = (float)p.X0;
    p.Y0f = (float)p.Y0;
    p.SXf = (float)p.SX;
    p.SYf = (float)p.SY;
    p.slope = p.DX > 0 ? (float)p.DY / (float)p.DX : 0.f;
    return p;
}

// Closed-form Bresenham move count at step i (exact; requires DX > 0).
__device__ inline int line_m(const LineP& p, int i) {
    return (int)((unsigned)(2 * p.DY * i + p.DX) / (unsigned)(2 * p.DX));
}

// tmax candidate pixel (R7's dedup set): drive i in [-3, cnt+3], other offset
// o in [-8,8] around the clamped Bresenham row — superset of all nonzero pixels.
__device__ inline void cand_pixel(const LineP& p, int e, int& r, int& c) {
    int ii = e / ORANGE - 3;
    int o = e - (ii + 3) * ORANGE - 8;
    int d = p.X0 + ii * p.SX;
    int icl = ii < 0 ? 0 : (ii > p.cnt - 1 ? p.cnt - 1 : ii);
    int m = p.cnt > 0 ? line_m(p, icl) : 0;
    int u = p.Y0 + m * p.SY + o;
    r = p.steep ? d : u;
    c = p.steep ? u : d;
}

// Exact conv value at pixel (r,c): taps over <=7 nearby line pixels + endpoint.
__device__ inline float conv_at(const LineP& p, int r, int c, const float* keff) {
    int t = p.steep ? r : c;
    int u = p.steep ? c : r;
    float w = 0.f;
    if (p.cnt > 0) {
        int icen = (t - p.X0) * p.SX;
        if (icen >= -3 && icen <= p.cnt + 2) {
            int ilo = icen - 3 < 0 ? 0 : icen - 3;
            int ihi = icen + 3 > p.cnt - 1 ? p.cnt - 1 : icen + 3;
            for (int i = ilo; i <= ihi; ++i) {
                int m = line_m(p, i);
                int other = p.Y0 + m * p.SY;
                int d_other = u - other;
                if (d_other >= -3 && d_other <= 3) {
                    int d_drive = (icen - i) * p.SX;
                    int d_row = p.steep ? d_drive : d_other;
                    int d_col = p.steep ? d_other : d_drive;
                    w += keff[(3 - d_row) * 7 + (3 - d_col)];
                }
            }
        }
    }
    int dr = r - p.ey, dc = c - p.ex;
    if (dr >= -3 && dr <= 3 && dc >= -3 && dc <= 3)
        w += keff[(3 - dr) * 7 + (3 - dc)];
    return w;
}

// Ownership predicate: true -> quad (row r, cols [c0,c0+3]) is band-owned
// (written with values by phase B), false -> fill-owned (zeroed).
// noinline => ONE compiled copy => bit-identical decision at both call sites,
// so the partition is exact (no double-write, no unwritten quad).
// Sufficiency margins (every nonzero pixel's quad is P-true):
//  endpoint: exact rect.  non-steep: |r-est(ic_center)| <= 3 + (4.5*slope+0.5)
//  <= 8 < 8.5.  steep: col dist <= 3 + (3*slope+0.5) <= 6.5 < 7.
__device__ __attribute__((noinline)) bool quadP(const LineP& p, int r, int c0) {
    if (r >= p.ey - 3 && r <= p.ey + 3 && c0 <= p.ex + 3 && c0 + 3 >= p.ex - 3)
        return true;
    if (p.cnt <= 0) return false;
    if (!p.steep) {
        float ic = ((float)c0 + 1.5f - p.X0f) * p.SXf;
        if (ic < -5.0f || ic > (float)p.cnt + 4.0f) return false;
        float est = p.Y0f + p.SYf * p.slope * ic;
        return fabsf((float)r - est) <= 8.5f;
    } else {
        float ic = ((float)r - p.X0f) * p.SXf;
        if (ic < -3.5f || ic > (float)p.cnt + 2.5f) return false;
        float est = p.Y0f + p.SYf * p.slope * ic;
        return ((float)c0 <= est + 7.0f) && ((float)(c0 + 3) >= est - 7.0f);
    }
}

__global__ void __launch_bounds__(256)
k_fused(const float* x0p, const float* y0p, const float* x1p, const float* y1p,
        const float* __restrict__ kern, int* __restrict__ ws,
        float* __restrict__ out) {
    const int tid = threadIdx.x, bid = blockIdx.x;
    const int gid = bid * 256 + tid;
    const int Q = NN / 4;
    LineP p = load_params(x0p, y0p, x1p, y1p);
    f4* o4 = (f4*)out;

    // Fill phase: zero all fill-owned quads (band-owned ones are written below).
    {
        int pix = gid << 2;
        int r = pix >> 11, c0 = pix & (N - 1);
        if (!quadP(p, r, c0)) {
            f4 z = {0.f, 0.f, 0.f, 0.f};
            __builtin_nontemporal_store(z, &o4[gid]);
            __builtin_nontemporal_store(z, &o4[gid + Q]);
            __builtin_nontemporal_store(z, &o4[gid + 2 * Q]);
        }
    }
    if (bid >= CB) return;

    __shared__ float keff[TAPS];
    __shared__ float sred[4];
    __shared__ float stmax;
    if (tid < TAPS)
        keff[tid] = kern[tid] + kern[TAPS + tid] + kern[2 * TAPS + tid];
    __syncthreads();

    // Phase A: per-block band max over the dedup candidate set, publish.
    float v = 0.f;
    int totalc = (p.cnt + 7) * ORANGE;
    if (gid < totalc) {
        int r, c;
        cand_pixel(p, gid, r, c);
        if ((unsigned)r < (unsigned)N && (unsigned)c < (unsigned)N)
            v = conv_at(p, r, c, keff);
    }
    for (int off = 32; off; off >>= 1) v = fmaxf(v, __shfl_down(v, off));
    if ((tid & 63) == 0) sred[tid >> 6] = v;
    __syncthreads();
    if (tid == 0) {
        v = fmaxf(fmaxf(sred[0], sred[1]), fmaxf(sred[2], sred[3]));
        atomicExch(&ws[bid], __float_as_int(v));
        __threadfence();
        atomicExch(&ws[256 + bid], MAGIC);
    }

    // Spin-gather all CB partials (device-scope atomics; producers==spinners,
    // fill blocks never wait -> forward progress guaranteed).
    float pv = 0.f;
    if (tid < CB) {
        while (atomicAdd(&ws[256 + tid], 0) != MAGIC)
            __builtin_amdgcn_s_sleep(2);
        __threadfence();
        pv = __int_as_float(atomicAdd(&ws[tid], 0));
    }
    for (int off = 32; off; off >>= 1) pv = fmaxf(pv, __shfl_down(pv, off));
    __syncthreads();                       // phase-A sred reads done
    if ((tid & 63) == 0) sred[tid >> 6] = pv;
    __syncthreads();
    if (tid == 0)
        stmax = fmaxf(fmaxf(sred[0], sred[1]), fmaxf(sred[2], sred[3]));
    __syncthreads();
    float scale = 1.f / stmax;

    // Phase B: enumerate a superset of band-owned quads, filter by quadP, write.
    int r2 = -1, c02 = -1;
    if (gid < 21) {                        // endpoint rect: 7 rows x <=3 quads
        r2 = p.ey - 3 + gid / 3;
        c02 = ((p.ex - 3) & ~3) + 4 * (gid % 3);
    } else if (p.cnt > 0) {
        int li = gid - 21;
        if (!p.steep) {                    // 19 rows per drive-quad-column
            int tend = p.X0 + p.cnt * p.SX;
            int cmin = (p.X0 < tend ? p.X0 : tend) - 7;
            int cmax = (p.X0 > tend ? p.X0 : tend) + 4;
            int cbase = cmin & ~3;
            int nq = ((cmax - cbase) >> 2) + 1;
            int k = li / 19, dr = li - k * 19;
            if (k < nq) {
                c02 = cbase + 4 * k;
                float ic = ((float)c02 + 1.5f - p.X0f) * p.SXf;
                float est = p.Y0f + p.SYf * p.slope * ic;
                r2 = (int)floorf(est) - 9 + dr;
            }
        } else {                           // 5 quad-cols per drive-row
            int k = li / 5, j = li - k * 5;
            if (k <= p.cnt + 6) {
                r2 = p.X0 + (k - 3) * p.SX;
                float ic = (float)((r2 - p.X0) * p.SX);
                float est = p.Y0f + p.SYf * p.slope * ic;
                c02 = ((((int)floorf(est) - 10) & ~3)) + 4 * j;
            }
        }
    }
    if (r2 >= 0 && r2 < N && c02 >= 0 && c02 <= N - 4 && quadP(p, r2, c02)) {
        f4 w;
        w.x = conv_at(p, r2, c02,     keff) * scale;
        w.y = conv_at(p, r2, c02 + 1, keff) * scale;
        w.z = conv_at(p, r2, c02 + 2, keff) * scale;
        w.w = conv_at(p, r2, c02 + 3, keff) * scale;
        int qid = (r2 << 9) + (c02 >> 2);
        __builtin_nontemporal_store(w, &o4[qid]);
        __builtin_nontemporal_store(w, &o4[qid + Q]);
        __builtin_nontemporal_store(w, &o4[qid + 2 * Q]);
    }
}

extern "C" void kernel_launch(void* const* d_in, const int* in_sizes, int n_in,
                              void* d_out, int out_size, void* d_ws, size_t ws_size,
                              hipStream_t stream) {
    const float* x0 = (const float*)d_in[0];
    const float* y0 = (const float*)d_in[1];
    const float* x1 = (const float*)d_in[2];
    const float* y1 = (const float*)d_in[3];
    const float* kern = (const float*)d_in[4];
    k_fused<<<GRID, 256, 0, stream>>>(x0, y0, x1, y1, kern, (int*)d_ws,
                                      (float*)d_out);
}